// Round 4
// baseline (867.377 us; speedup 1.0000x reference)
//
#include <hip/hip_runtime.h>
#include <stdint.h>

#define BATCH 65536
#define KCAT 832   // 320 (state+action) + 512 (h)

typedef __attribute__((ext_vector_type(8))) short bf16x8;
typedef __attribute__((ext_vector_type(4))) float f32x4;

typedef __attribute__((address_space(3))) void lds_void_t;
typedef __attribute__((address_space(1))) void glob_void_t;

__device__ __forceinline__ void async_copy16(const void* g, void* l) {
  __builtin_amdgcn_global_load_lds((glob_void_t*)(uintptr_t)g,
                                   (lds_void_t*)(uint32_t)(uintptr_t)l, 16, 0, 0);
}

__device__ __forceinline__ float b2f(unsigned short u) {
  union { uint32_t i; float f; } c; c.i = ((uint32_t)u) << 16; return c.f;
}
__device__ __forceinline__ unsigned short f2b(float f) {
  uint32_t x = __float_as_uint(f);
  uint32_t r = (x + 0x7fffu + ((x >> 16) & 1u)) >> 16;
  return (unsigned short)r;
}

// ---------------- prep kernels ----------------

__global__ void pack_A(const float* __restrict__ state, const float* __restrict__ action,
                       const float* __restrict__ hidden, unsigned short* __restrict__ Acat) {
  long t = (long)blockIdx.x * 256 + threadIdx.x;   // 65536*104 threads
  int seg = (int)(t % 104); long row = t / 104;
  int col = seg * 8;
  const float* src;
  if (col < 256)       src = state  + row * 256 + col;
  else if (col < 320)  src = action + row * 64  + (col - 256);
  else                 src = hidden + row * 512 + (col - 320);
  bf16x8 o;
  #pragma unroll
  for (int j = 0; j < 8; j++) o[j] = (short)f2b(src[j]);
  *(bf16x8*)(Acat + row * (size_t)KCAT + col) = o;
}

__global__ void pack_W(const float* __restrict__ w_ih, const float* __restrict__ w_hh,
                       unsigned short* __restrict__ Wrz, unsigned short* __restrict__ Wn) {
  long t = (long)blockIdx.x * 256 + threadIdx.x;   // 1536*104 threads
  int seg = (int)(t % 104); int j = (int)(t / 104); // row 0..1535
  int col = seg * 8;
  const float* src = (col < 320) ? (w_ih + (long)j * 320 + col)
                                 : (w_hh + (long)j * 512 + (col - 320));
  unsigned short* dst = (j < 1024) ? (Wrz + (long)j * KCAT + col)
                                   : (Wn + (long)(j - 1024) * KCAT + col);
  bf16x8 o;
  #pragma unroll
  for (int jj = 0; jj < 8; jj++) o[jj] = (short)f2b(src[jj]);
  *(bf16x8*)dst = o;
}

// also initializes q_out to b3 (G4 accumulates into it atomically)
__global__ void pack_w12(const float* __restrict__ w1, const float* __restrict__ w2,
                         const float* __restrict__ b3,
                         unsigned short* __restrict__ w1b, unsigned short* __restrict__ w2b,
                         float* __restrict__ q) {
  long t = (long)blockIdx.x * 256 + threadIdx.x;   // 262144 threads
  if (t < 65536) {
    const float* s = w1 + t * 8; unsigned short* d = w1b + t * 8;
    bf16x8 o;
    #pragma unroll
    for (int j = 0; j < 8; j++) o[j] = (short)f2b(s[j]);
    *(bf16x8*)d = o;
  } else if (t < 196608) {
    long t2 = t - 65536;
    const float* s = w2 + t2 * 8; unsigned short* d = w2b + t2 * 8;
    bf16x8 o;
    #pragma unroll
    for (int j = 0; j < 8; j++) o[j] = (short)f2b(s[j]);
    *(bf16x8*)d = o;
  } else {
    q[t - 196608] = b3[0];
  }
}

// ---------------- fused GRU: r,z,n GEMMs + elementwise ----------------
// Per block: 128 rows x 64 gate-cols. Accumulates r,z (K=832) and i_n (K=320),
// h_n (K=512) in registers; epilogue applies the full GRU cell.
// Double-buffered LDS staging: tile kt+1 issued before compute(kt), one barrier/iter.

__global__ __launch_bounds__(256, 2) void gru_fused(
    const unsigned short* __restrict__ A,    // A_cat [BATCH x 832] bf16
    const unsigned short* __restrict__ Wrz,  // [1024 x 832] bf16 (r rows 0..511, z rows 512..1023)
    const unsigned short* __restrict__ Wn,   // [512 x 832] bf16
    const float* __restrict__ b_ih, const float* __restrict__ b_hh,
    float* __restrict__ hnew_f,              // d_out + BATCH, f32 [BATCH x 512]
    unsigned short* __restrict__ hnew_b)     // bf16 copy for next GEMM
{
  __shared__ unsigned short Asm[2][128 * 64];    // 32 KB
  __shared__ unsigned short Wsm[2][3 * 4096];    // 48 KB (r | z | n)
  const int tid = threadIdx.x;
  const int wave = tid >> 6, lane = tid & 63;
  const int wm = wave >> 1, wn = wave & 1;

  const int bid = blockIdx.x;
  const int xcd = bid & 7;
  const int j = bid >> 3;          // 0..511 per-XCD work id
  const int bn = j & 7;            // 8 col tiles of 64
  const long bm = (long)xcd * 64 + (j >> 3);   // 512 row tiles of 128

  const int srow = lane >> 3;                       // 0..7
  const int scol = (((lane & 7) ^ srow)) * 8;       // swizzled k-segment fetched by this lane

  f32x4 accR[4][2], accZ[4][2], accI[4][2], accH[4][2];
  #pragma unroll
  for (int i = 0; i < 4; i++)
    #pragma unroll
    for (int t = 0; t < 2; t++) {
      accR[i][t] = (f32x4){0.f,0.f,0.f,0.f}; accZ[i][t] = (f32x4){0.f,0.f,0.f,0.f};
      accI[i][t] = (f32x4){0.f,0.f,0.f,0.f}; accH[i][t] = (f32x4){0.f,0.f,0.f,0.f};
    }

  const unsigned short* Ag  = A   + (bm * 128 + wave * 8 + srow) * (size_t)KCAT + scol;
  const unsigned short* Wrg = Wrz + ((size_t)bn * 64 + wave * 8 + srow) * KCAT + scol;
  const unsigned short* Wzg = Wrz + ((size_t)512 + bn * 64 + wave * 8 + srow) * KCAT + scol;
  const unsigned short* Wng = Wn  + ((size_t)bn * 64 + wave * 8 + srow) * KCAT + scol;

  const int rlo = lane & 15;
  const int quad = lane >> 4;

  auto issue = [&](int kt, int b) {
    #pragma unroll
    for (int t = 0; t < 4; ++t)
      async_copy16(Ag + (size_t)(t * 32) * KCAT + kt * 64, &Asm[b][(t * 32 + wave * 8) * 64]);
    #pragma unroll
    for (int t = 0; t < 2; ++t) {
      async_copy16(Wrg + (size_t)(t * 32) * KCAT + kt * 64, &Wsm[b][0 * 4096 + (t * 32 + wave * 8) * 64]);
      async_copy16(Wzg + (size_t)(t * 32) * KCAT + kt * 64, &Wsm[b][1 * 4096 + (t * 32 + wave * 8) * 64]);
      async_copy16(Wng + (size_t)(t * 32) * KCAT + kt * 64, &Wsm[b][2 * 4096 + (t * 32 + wave * 8) * 64]);
    }
  };

  issue(0, 0);
  __syncthreads();

  for (int kt = 0; kt < 13; ++kt) {
    const int cb = kt & 1;
    if (kt < 12) issue(kt + 1, (kt + 1) & 1);

    #pragma unroll
    for (int ks = 0; ks < 2; ++ks) {
      const int kseg = ks * 4 + quad;                 // global k-segment 0..7
      const int sw = (kseg ^ (rlo & 7)) * 8;          // swizzled LDS element offset
      bf16x8 af[4], bR[2], bZ[2], bN[2];
      #pragma unroll
      for (int mt = 0; mt < 4; mt++)
        af[mt] = *(const bf16x8*)&Asm[cb][(wm * 64 + mt * 16 + rlo) * 64 + sw];
      #pragma unroll
      for (int nt = 0; nt < 2; nt++) {
        const int wrow = (wn * 32 + nt * 16 + rlo) * 64 + sw;
        bR[nt] = *(const bf16x8*)&Wsm[cb][0 * 4096 + wrow];
        bZ[nt] = *(const bf16x8*)&Wsm[cb][1 * 4096 + wrow];
        bN[nt] = *(const bf16x8*)&Wsm[cb][2 * 4096 + wrow];
      }
      #pragma unroll
      for (int mt = 0; mt < 4; mt++)
        #pragma unroll
        for (int nt = 0; nt < 2; nt++) {
          accR[mt][nt] = __builtin_amdgcn_mfma_f32_16x16x32_bf16(af[mt], bR[nt], accR[mt][nt], 0, 0, 0);
          accZ[mt][nt] = __builtin_amdgcn_mfma_f32_16x16x32_bf16(af[mt], bZ[nt], accZ[mt][nt], 0, 0, 0);
        }
      if (kt < 5) {   // k in [0,320): state+action part -> i_n
        #pragma unroll
        for (int mt = 0; mt < 4; mt++)
          #pragma unroll
          for (int nt = 0; nt < 2; nt++)
            accI[mt][nt] = __builtin_amdgcn_mfma_f32_16x16x32_bf16(af[mt], bN[nt], accI[mt][nt], 0, 0, 0);
      } else {        // k in [320,832): h part -> h_n
        #pragma unroll
        for (int mt = 0; mt < 4; mt++)
          #pragma unroll
          for (int nt = 0; nt < 2; nt++)
            accH[mt][nt] = __builtin_amdgcn_mfma_f32_16x16x32_bf16(af[mt], bN[nt], accH[mt][nt], 0, 0, 0);
      }
    }
    __syncthreads();   // drains kt+1 loads (issued before compute -> head start)
  }

  // epilogue: C/D layout col=lane&15, row=quad*4+reg
  const long rowbase = bm * 128 + wm * 64;
  const int colbase = bn * 64 + wn * 32;
  #pragma unroll
  for (int mt = 0; mt < 4; mt++) {
    #pragma unroll
    for (int nt = 0; nt < 2; nt++) {
      const int col = colbase + nt * 16 + rlo;   // 0..511
      const float brv = b_ih[col] + b_hh[col];
      const float bzv = b_ih[512 + col] + b_hh[512 + col];
      const float bin = b_ih[1024 + col];
      const float bhn = b_hh[1024 + col];
      #pragma unroll
      for (int i = 0; i < 4; i++) {
        const long row = rowbase + mt * 16 + quad * 4 + i;
        const float r = 1.f / (1.f + __expf(-(accR[mt][nt][i] + brv)));
        const float z = 1.f / (1.f + __expf(-(accZ[mt][nt][i] + bzv)));
        const float x = (accI[mt][nt][i] + bin) + r * (accH[mt][nt][i] + bhn);
        const float n = 1.f - 2.f / (__expf(2.f * x) + 1.f);   // tanh(x)
        const float h = b2f(A[row * (size_t)KCAT + 320 + col]); // h in bf16 from A_cat
        const float hv = (1.f - z) * n + z * h;
        hnew_f[row * (size_t)512 + col] = hv;
        hnew_b[row * (size_t)512 + col] = f2b(hv);
      }
    }
  }
}

// ---------------- generic TN GEMM: relu(A @ W^T + bias) ----------------
// 128x128 tile, BK=64, XCD-swizzled 1-D grid of 4096 (M=65536, N=1024).
// Double-buffered staging. QFUSE=0: store bf16. QFUSE=1: q[row] += relu(v).w3 (atomic).

template<int KT, int QFUSE>
__global__ __launch_bounds__(256, 2) void gemm_bt(
    const unsigned short* __restrict__ A, const unsigned short* __restrict__ W,
    const float* __restrict__ bias, unsigned short* __restrict__ out,
    int lda, const float* __restrict__ w3, float* __restrict__ q)
{
  __shared__ unsigned short Asm[2][128 * 64];
  __shared__ unsigned short Bsm[2][128 * 64];
  const int tid = threadIdx.x;
  const int wave = tid >> 6, lane = tid & 63;
  const int wm = wave >> 1, wn = wave & 1;

  const int bid = blockIdx.x;
  const int xcd = bid & 7;
  const int j = bid >> 3;
  const int bn = j & 7;                        // 8 col tiles of 128 (N=1024)
  const long bm = (long)xcd * 64 + (j >> 3);   // 512 row tiles of 128

  const int srow = lane >> 3;
  const int scol = (((lane & 7) ^ srow)) * 8;  // swizzled fetch segment

  f32x4 acc[4][4];
  #pragma unroll
  for (int i = 0; i < 4; i++)
    #pragma unroll
    for (int t = 0; t < 4; t++) acc[i][t] = (f32x4){0.f, 0.f, 0.f, 0.f};

  const unsigned short* Ag = A + (bm * 128 + wave * 8 + srow) * (size_t)lda + scol;
  const unsigned short* Wg = W + ((size_t)bn * 128 + wave * 8 + srow) * lda + scol;

  const int rlo = lane & 15;
  const int quad = lane >> 4;

  auto issue = [&](int kt, int b) {
    #pragma unroll
    for (int t = 0; t < 4; ++t)
      async_copy16(Ag + (size_t)(t * 32) * lda + kt * 64, &Asm[b][(t * 32 + wave * 8) * 64]);
    #pragma unroll
    for (int t = 0; t < 4; ++t)
      async_copy16(Wg + (size_t)(t * 32) * lda + kt * 64, &Bsm[b][(t * 32 + wave * 8) * 64]);
  };

  issue(0, 0);
  __syncthreads();

  for (int kt = 0; kt < KT; ++kt) {
    const int cb = kt & 1;
    if (kt + 1 < KT) issue(kt + 1, (kt + 1) & 1);

    #pragma unroll
    for (int ks = 0; ks < 2; ++ks) {
      const int kseg = ks * 4 + quad;
      const int sw = (kseg ^ (rlo & 7)) * 8;
      bf16x8 af[4], bfv[4];
      #pragma unroll
      for (int mt = 0; mt < 4; mt++)
        af[mt] = *(const bf16x8*)&Asm[cb][(wm * 64 + mt * 16 + rlo) * 64 + sw];
      #pragma unroll
      for (int nt = 0; nt < 4; nt++)
        bfv[nt] = *(const bf16x8*)&Bsm[cb][(wn * 64 + nt * 16 + rlo) * 64 + sw];
      #pragma unroll
      for (int mt = 0; mt < 4; mt++)
        #pragma unroll
        for (int nt = 0; nt < 4; nt++)
          acc[mt][nt] = __builtin_amdgcn_mfma_f32_16x16x32_bf16(af[mt], bfv[nt], acc[mt][nt], 0, 0, 0);
    }
    __syncthreads();
  }

  if (QFUSE == 0) {
    #pragma unroll
    for (int mt = 0; mt < 4; mt++) {
      #pragma unroll
      for (int nt = 0; nt < 4; nt++) {
        const int col = bn * 128 + wn * 64 + nt * 16 + rlo;
        const float bv = bias[col];
        #pragma unroll
        for (int i = 0; i < 4; i++) {
          const long row = bm * 128 + wm * 64 + mt * 16 + quad * 4 + i;
          float v = fmaxf(acc[mt][nt][i] + bv, 0.f);
          out[row * (size_t)1024 + col] = f2b(v);
        }
      }
    }
  } else {
    // fused final dot: q[row] += sum_col relu(v) * w3[col]
    float bv[4], w3v[4];
    #pragma unroll
    for (int nt = 0; nt < 4; nt++) {
      const int col = bn * 128 + wn * 64 + nt * 16 + rlo;
      bv[nt] = bias[col];
      w3v[nt] = w3[col];
    }
    #pragma unroll
    for (int mt = 0; mt < 4; mt++) {
      #pragma unroll
      for (int i = 0; i < 4; i++) {
        float s = 0.f;
        #pragma unroll
        for (int nt = 0; nt < 4; nt++)
          s += fmaxf(acc[mt][nt][i] + bv[nt], 0.f) * w3v[nt];
        // reduce the 16 lanes of the quad (same row, different cols)
        #pragma unroll
        for (int off = 1; off < 16; off <<= 1) s += __shfl_xor(s, off, 64);
        if (rlo == 0) {
          const long row = bm * 128 + wm * 64 + mt * 16 + quad * 4 + i;
          atomicAdd(&q[row], s);
        }
      }
    }
  }
}

// ---------------- launch ----------------

extern "C" void kernel_launch(void* const* d_in, const int* in_sizes, int n_in,
                              void* d_out, int out_size, void* d_ws, size_t ws_size,
                              hipStream_t stream) {
  const float* state  = (const float*)d_in[0];
  const float* action = (const float*)d_in[1];
  const float* hidden = (const float*)d_in[2];
  const float* w_ih   = (const float*)d_in[3];
  const float* w_hh   = (const float*)d_in[4];
  const float* b_ih   = (const float*)d_in[5];
  const float* b_hh   = (const float*)d_in[6];
  const float* w1     = (const float*)d_in[7];
  const float* b1     = (const float*)d_in[8];
  const float* w2     = (const float*)d_in[9];
  const float* b2     = (const float*)d_in[10];
  const float* w3     = (const float*)d_in[11];
  const float* b3     = (const float*)d_in[12];

  float* q_out = (float*)d_out;
  float* h_out = q_out + BATCH;

  char* ws = (char*)d_ws;
  // region 0 [0, 128MB): Acat (109 MB) in phase 1, then reused as x1 (128 MB)
  unsigned short* Acat = (unsigned short*)(ws + 0);
  unsigned short* x1   = (unsigned short*)(ws + 0);
  // region 2 [256MB, 320MB): hnb (64 MB)
  unsigned short* hnb  = (unsigned short*)(ws + 268435456);
  // region 3: packed weights
  unsigned short* Wrz  = (unsigned short*)(ws + 335544320);    // 1024x832 bf16
  unsigned short* Wn   = (unsigned short*)(ws + 337248256);    // 512x832 bf16
  unsigned short* w1b  = (unsigned short*)(ws + 338100224);    // 1024x512 bf16
  unsigned short* w2b  = (unsigned short*)(ws + 339148800);    // 1024x1024 bf16

  pack_A<<<26624, 256, 0, stream>>>(state, action, hidden, Acat);
  pack_W<<<624, 256, 0, stream>>>(w_ih, w_hh, Wrz, Wn);
  pack_w12<<<1024, 256, 0, stream>>>(w1, w2, b3, w1b, w2b, q_out);

  // fused GRU: r,z,i_n,h_n GEMMs (K=832) + GRU cell -> h_out (f32) + hnb (bf16)
  gru_fused<<<4096, 256, 0, stream>>>(Acat, Wrz, Wn, b_ih, b_hh, h_out, hnb);
  // x1 = relu(h_new @ w1^T + b1)  K=512   (writes over Acat region; Acat is dead)
  gemm_bt<8, 0><<<4096, 256, 0, stream>>>(hnb, w1b, b1, x1, 512, nullptr, nullptr);
  // q += relu(x1 @ w2^T + b2) . w3  K=1024  (x2 never materialized)
  gemm_bt<16, 1><<<4096, 256, 0, stream>>>(x1, w2b, b2, nullptr, 1024, w3, q_out);
}